// Round 15
// baseline (248.979 us; speedup 1.0000x reference)
//
#include <hip/hip_runtime.h>
#include <hip/hip_bf16.h>
#include <math.h>

typedef __bf16 bf16x4 __attribute__((ext_vector_type(4)));
typedef __bf16 bf16x8 __attribute__((ext_vector_type(8)));
typedef float  f32x4  __attribute__((ext_vector_type(4)));

#define S_LEN 2048
#define BATCH 4
#define DMODEL 1280
#define NHEAD 16
#define DHEAD 80
#define KDIM 1280

__device__ __forceinline__ f32x4 mfma_bf16(bf16x8 a, bf16x8 b, f32x4 c) {
  return __builtin_amdgcn_mfma_f32_16x16x32_bf16(a, b, c, 0, 0, 0);
}

__device__ __forceinline__ void gload16(const void* g, void* l) {
  __builtin_amdgcn_global_load_lds(
      (const __attribute__((address_space(1))) unsigned int*)g,
      (__attribute__((address_space(3))) unsigned int*)l, 16, 0, 0);
}

__device__ __forceinline__ bf16x8 shfl8(bf16x8 v, int srcLane) {
  union { bf16x8 b; int i[4]; } u, r;
  u.b = v;
#pragma unroll
  for (int t = 0; t < 4; ++t) r.i[t] = __shfl(u.i[t], srcLane, 64);
  return r.b;
}

// ---------------- fp32 -> bf16 cast (vectorized) ----------------
__global__ void cast_f32_to_bf16(const float* __restrict__ in,
                                 __bf16* __restrict__ out, int n4) {
  int i = blockIdx.x * 256 + threadIdx.x;
  if (i >= n4) return;
  float4 v = reinterpret_cast<const float4*>(in)[i];
  bf16x4 o;
  o[0] = (__bf16)v.x; o[1] = (__bf16)v.y; o[2] = (__bf16)v.z; o[3] = (__bf16)v.w;
  reinterpret_cast<bf16x4*>(out)[i] = o;
}

// ---------------- sin/cos tables [S][40] ----------------
__global__ void build_sincos(const float* __restrict__ rot,
                             float* __restrict__ ctab, float* __restrict__ stab, int n) {
  int i = blockIdx.x * 256 + threadIdx.x;
  if (i >= n) return;
  float v = rot[i];
  ctab[i] = cosf(v);
  stab[i] = sinf(v);
}

// ---------------- zero page ----------------
__global__ void zero_fill(float* __restrict__ p, int n) {
  int i = blockIdx.x * 256 + threadIdx.x;
  if (i < n) p[i] = 0.0f;
}

// ---------------- QKV GEMM, 128x128 tile, BK=64, 4 waves, SINGLE 32KB buffer ----------------
// (unchanged from R11: R9 main loop + vector-store epilogue)
__global__ __launch_bounds__(256, 4) void gemm_qkv128(
    const __bf16* __restrict__ A, const __bf16* __restrict__ Bw,
    const float* __restrict__ bias,
    __bf16* __restrict__ qw, __bf16* __restrict__ kw, __bf16* __restrict__ vtw)
{
  __shared__ __align__(1024) char smem[32768];  // A 16KB | B 16KB; reused as C-tile in epilogue
  const int tid = threadIdx.x;
  const int lane = tid & 63;
  const int w = tid >> 6;             // 0..3
  const int lr = lane & 15, lg = lane >> 4;
  const int wr = w >> 1, wc = w & 1;  // wave owns rows wr*64..+64, cols wc*64..+64

  // XCD-chunked swizzle: 8 bx-panels per XCD (A slice 2.6 MB, L2-resident)
  const int wg = blockIdx.x;          // 0..1919
  const int xcd = wg & 7, idx = wg >> 3;  // idx 0..239
  const int bx = xcd * 8 + (idx & 7);
  const int by = idx >> 3;            // 0..29
  const int r0 = bx * 128, c0 = by * 128;
  const char* asrc = (const char*)(A + (size_t)r0 * KDIM);
  const char* bsrc = (const char*)(Bw + (size_t)c0 * KDIM);

  f32x4 acc[4][4] = {};

  for (int t = 0; t < 20; ++t) {
    const size_t kb = (size_t)t * 128;  // byte offset into K dim
#pragma unroll
    for (int i = 0; i < 8; ++i) {
      const int L = i * 4096 + tid * 16;           // 0..32767
      const int r = (L & 16383) >> 7;              // row within A or B panel
      const int coff = (L & 127) ^ ((r & 7) << 4); // inverse-swizzled source
      const char* s = (L < 16384 ? asrc : bsrc) + (size_t)r * 2560 + kb + coff;
      gload16(s, &smem[L]);
    }
    __syncthreads();  // drains vmcnt+lgkm; other blocks on the CU fill the gap

#pragma unroll
    for (int kk = 0; kk < 2; ++kk) {
      bf16x8 af[4], bfr[4];
#pragma unroll
      for (int rf = 0; rf < 4; ++rf) {
        const int row = wr * 64 + rf * 16 + lr;
        af[rf] = *reinterpret_cast<const bf16x8*>(
            &smem[row * 128 + ((kk * 64 + lg * 16) ^ ((row & 7) << 4))]);
      }
#pragma unroll
      for (int cf = 0; cf < 4; ++cf) {
        const int row = wc * 64 + cf * 16 + lr;
        bfr[cf] = *reinterpret_cast<const bf16x8*>(
            &smem[16384 + row * 128 + ((kk * 64 + lg * 16) ^ ((row & 7) << 4))]);
      }
#pragma unroll
      for (int rf = 0; rf < 4; ++rf)
#pragma unroll
        for (int cf = 0; cf < 4; ++cf)
          acc[rf][cf] = mfma_bf16(af[rf], bfr[cf], acc[rf][cf]);
    }
    __syncthreads();  // reads done -> next stage may overwrite
  }

  // ---- epilogue ----
  float biasr[4];
#pragma unroll
  for (int cf = 0; cf < 4; ++cf) biasr[cf] = bias[c0 + wc * 64 + cf * 16 + lr];

  // stage C-tile to LDS: row-major [128 rows][128 cols] bf16, col-XOR swizzle
#pragma unroll
  for (int cf = 0; cf < 4; ++cf) {
    const int col = wc * 64 + cf * 16 + lr;
#pragma unroll
    for (int rf = 0; rf < 4; ++rf)
#pragma unroll
      for (int j = 0; j < 4; ++j) {
        const int row = wr * 64 + rf * 16 + lg * 4 + j;
        *reinterpret_cast<__bf16*>(
            &smem[row * 256 + ((col ^ ((row & 7) << 3)) << 1)]) =
            (__bf16)(acc[rf][cf][j] + biasr[cf]);
      }
  }
  __syncthreads();

  const int which = c0 / DMODEL;          // 0=q, 1=k, 2=v (block-uniform)
  const int ee0 = c0 - which * DMODEL;    // channel base within {q,k,v}

  if (which < 2) {
    __bf16* dst = (which == 0) ? qw : kw;
#pragma unroll
    for (int i = 0; i < 8; ++i) {
      const int cid = i * 256 + tid;      // 0..2047
      const int row = cid >> 4, slot = cid & 15;
      bf16x8 v = *reinterpret_cast<const bf16x8*>(
          &smem[row * 256 + ((slot ^ (row & 7)) << 4)]);
      const int tr = r0 + row;
      const int b = tr & 3, stok = tr >> 2;
      const int ee = ee0 + slot * 8;      // 8-aligned; 8|80 -> never straddles a head
      const int h = ee / DHEAD, dh = ee - h * DHEAD;
      *reinterpret_cast<bf16x8*>(
          &dst[((size_t)(b * NHEAD + h) * S_LEN + stok) * DHEAD + dh]) = v;
    }
  } else {
    const int s0 = r0 >> 2;               // 32-aligned token/4 base
#pragma unroll
    for (int i = 0; i < 8; ++i) {
      const int cid = i * 256 + tid;      // 0..2047
      const int col = cid >> 4;           // channel within tile, 0..127
      const int b = (cid >> 2) & 3, spblk = cid & 3;
      bf16x8 v;
#pragma unroll
      for (int k = 0; k < 8; ++k) {
        const int spl = spblk * 8 + k;
        // inverse sigma: s = (sp&3) | ((sp&24)>>1) | ((sp&4)<<2)
        const int sl = (spl & 3) | ((spl & 24) >> 1) | ((spl & 4) << 2);
        const int row = sl * 4 + b;
        v[k] = *reinterpret_cast<const __bf16*>(
            &smem[row * 256 + ((col ^ ((row & 7) << 3)) << 1)]);
      }
      const int ee = ee0 + col;
      const int h = ee / DHEAD, dh = ee - h * DHEAD;
      *reinterpret_cast<bf16x8*>(
          &vtw[((size_t)(b * NHEAD + h) * DHEAD + dh) * S_LEN + s0 + spblk * 8]) = v;
    }
  }
}

// ---------------- out-proj GEMM (128x128, unchanged) ----------------
template <int MODE>
__global__ __launch_bounds__(256) void gemm_bt(
    const __bf16* __restrict__ A, const __bf16* __restrict__ Bw,
    const float* __restrict__ bias, float* __restrict__ outf)
{
  __shared__ __align__(16) char smem[2][2][16384];
  const int tid = threadIdx.x;
  const int lane = tid & 63;
  const int w = tid >> 6;
  const int lr = lane & 15, lg = lane >> 4;
  const int rowblk = (w >> 1) * 64, colblk = (w & 1) * 64;
  const int sxz = (lane & 7) << 4;

  const int wg = blockIdx.x;
  const int xcd = wg & 7, idx = wg >> 3;
  const int bx = xcd * 8 + (idx & 7);
  const int by = idx >> 3;
  const int r0 = bx * 128;
  const int c0 = by * 128;
  const char* asrc = (const char*)(A + (size_t)r0 * KDIM);
  const char* bsrc = (const char*)(Bw + (size_t)c0 * KDIM);

  f32x4 acc[4][4] = {};

  auto stage = [&](int buf, int kt) {
    const size_t kb = (size_t)kt * 128;
#pragma unroll
    for (int i = 0; i < 4; ++i) {
      int L = i * 4096 + tid * 16;
      int r = L >> 7;
      int coff = (L & 127) ^ ((r & 7) << 4);
      gload16(asrc + (size_t)r * 2560 + kb + coff, &smem[buf][0][L]);
      gload16(bsrc + (size_t)r * 2560 + kb + coff, &smem[buf][1][L]);
    }
  };

  auto compute = [&](int buf) {
#pragma unroll
    for (int kk = 0; kk < 2; ++kk) {
      const int cb = (kk * 64 + lg * 16) ^ sxz;
      bf16x8 af[4], bfr[4];
#pragma unroll
      for (int rf = 0; rf < 4; ++rf)
        af[rf] = *reinterpret_cast<const bf16x8*>(&smem[buf][0][(rowblk + rf * 16 + lr) * 128 + cb]);
#pragma unroll
      for (int cf = 0; cf < 4; ++cf)
        bfr[cf] = *reinterpret_cast<const bf16x8*>(&smem[buf][1][(colblk + cf * 16 + lr) * 128 + cb]);
#pragma unroll
      for (int rf = 0; rf < 4; ++rf)
#pragma unroll
        for (int cf = 0; cf < 4; ++cf)
          acc[rf][cf] = mfma_bf16(af[rf], bfr[cf], acc[rf][cf]);
    }
  };

  stage(0, 0);
  asm volatile("s_waitcnt vmcnt(0)" ::: "memory");
  __builtin_amdgcn_s_barrier();
  __builtin_amdgcn_sched_barrier(0);

  for (int t = 0; t < 20; ++t) {
    const int buf = t & 1;
    if (t < 19) {
      stage(buf ^ 1, t + 1);
      asm volatile("s_waitcnt vmcnt(8)" ::: "memory");
    } else {
      asm volatile("s_waitcnt vmcnt(0)" ::: "memory");
    }
    __builtin_amdgcn_sched_barrier(0);
    __builtin_amdgcn_s_barrier();
    __builtin_amdgcn_sched_barrier(0);

    compute(buf);

    __builtin_amdgcn_sched_barrier(0);
    __builtin_amdgcn_s_barrier();
    __builtin_amdgcn_sched_barrier(0);
  }

  float biasr[4];
#pragma unroll
  for (int cf = 0; cf < 4; ++cf) biasr[cf] = bias[c0 + colblk + cf * 16 + lr];

#pragma unroll
  for (int rf = 0; rf < 4; ++rf)
#pragma unroll
    for (int cf = 0; cf < 4; ++cf) {
      const int c = c0 + colblk + cf * 16 + lr;
#pragma unroll
      for (int j = 0; j < 4; ++j) {
        const int r = r0 + rowblk + rf * 16 + lg * 4 + j;
        outf[(size_t)r * DMODEL + c] = acc[rf][cf][j] + biasr[cf];
      }
    }
}

// ---------------- RoPE in-place on K ONLY (Q-rope fused into attn) ----------------
__global__ void rope_k_kernel(__bf16* __restrict__ kw,
                              const float* __restrict__ ctab, const float* __restrict__ stab)
{
  int idx = blockIdx.x * 256 + threadIdx.x;  // 64*2048*10 threads
  const int j = idx % 10;
  int rest = idx / 10;
  const int s = rest & (S_LEN - 1);
  const int bh = rest >> 11;                 // 0..63
  __bf16* base = kw + ((size_t)bh * S_LEN + s) * DHEAD;
  const float4 c4 = *reinterpret_cast<const float4*>(ctab + s * 40 + j * 4);
  const float4 s4 = *reinterpret_cast<const float4*>(stab + s * 40 + j * 4);
  bf16x4 a = *reinterpret_cast<bf16x4*>(base + j * 4);
  bf16x4 b = *reinterpret_cast<bf16x4*>(base + 40 + j * 4);
  const float cc[4] = {c4.x, c4.y, c4.z, c4.w};
  const float ss[4] = {s4.x, s4.y, s4.z, s4.w};
#pragma unroll
  for (int t = 0; t < 4; ++t) {
    float fa = (float)a[t], fb = (float)b[t];
    a[t] = (__bf16)(fa * cc[t] - fb * ss[t]);
    b[t] = (__bf16)(fb * cc[t] + fa * ss[t]);
  }
  *reinterpret_cast<bf16x4*>(base + j * 4) = a;
  *reinterpret_cast<bf16x4*>(base + 40 + j * 4) = b;
}

// ---------------- attention v9: v8 + fused in-register Q-RoPE (+qscale) ----------------
// Q partner mapping (40 = 32+8): element (ks,lg,j) pairs with (ks+-1, (lg+-1)&3, j),
// i.e. one shfl(lane+-16 mod 64) per fragment. lg>=2 padding of a2 stays exactly zero.
__global__ __launch_bounds__(256, 2) void attn_kernel(
    const __bf16* __restrict__ qw, const __bf16* __restrict__ kw,
    const __bf16* __restrict__ vtw, __bf16* __restrict__ ow,
    const float* __restrict__ zp,
    const float* __restrict__ ctab, const float* __restrict__ stab, float qscale)
{
  __shared__ __align__(1024) char smem[2][24576];  // [buf][K 12KB | V 10KB | 2KB trash]

  const int tid = threadIdx.x;
  const int lane = tid & 63;
  const int w = tid >> 6;             // 0..3
  const int lr = lane & 15, lg = lane >> 4;

  // XCD-aware mapping: all 8 q-tiles of one bh on one XCD
  const int wg = blockIdx.x;          // 0..511
  const int local = wg >> 3;          // 0..63
  const int bh = (wg & 7) * 8 + (local >> 3);
  const int qt = local & 7;

  const char* qbase = (const char*)(qw + ((size_t)bh * S_LEN + qt * 256) * DHEAD);
  const char* kbase = (const char*)(kw + (size_t)bh * S_LEN * DHEAD);
  const char* vbase = (const char*)(vtw + (size_t)bh * DHEAD * S_LEN);
  const char* zpb = (const char*)zp;

  bf16x8 z8, one8;
#pragma unroll
  for (int i = 0; i < 8; ++i) { z8[i] = (__bf16)0.0f; one8[i] = (__bf16)1.0f; }

  // Q fragments (B-operand), with RoPE + qscale applied in-register.
  bf16x8 aq[4][3];
  {
    const int upL = (lane + 16) & 63, dnL = (lane + 48) & 63;
#pragma unroll
    for (int m = 0; m < 4; ++m) {
      const int row = w * 64 + m * 16 + lr;
      const char* rp = qbase + (size_t)row * 160;
      bf16x8 a0 = *reinterpret_cast<const bf16x8*>(rp + lg * 16);
      bf16x8 a1 = *reinterpret_cast<const bf16x8*>(rp + 64 + lg * 16);
      bf16x8 a2 = (lg < 2) ? *reinterpret_cast<const bf16x8*>(rp + 128 + lg * 16) : z8;

      bf16x8 up1 = shfl8(a1, upL);   // a1 from lg+1
      bf16x8 up2 = shfl8(a2, upL);   // a2 from lg+1 (lg=3 -> lg0)
      bf16x8 dn0 = shfl8(a0, dnL);   // a0 from lg-1 (lg=0 -> lg3)
      bf16x8 dn1 = shfl8(a1, dnL);   // a1 from lg-1

      const int sg = qt * 256 + row; // global token position
      const float* cr = ctab + (size_t)sg * 40;
      const float* sr = stab + (size_t)sg * 40;

      // a0: d = 8lg+j (<40). partner q[d+40] = (lg<3) ? up1 : up2. sign -.
      {
        const int i0 = 8 * lg;
        float C[8], S[8];
#pragma unroll
        for (int j = 0; j < 8; ++j) { C[j] = cr[i0 + j]; S[j] = sr[i0 + j]; }
        bf16x8 p = (lg < 3) ? up1 : up2;
        bf16x8 o;
#pragma unroll
        for (int j = 0; j < 8; ++j)
          o[j] = (__bf16)((((float)a0[j]) * C[j] - ((float)p[j]) * S[j]) * qscale);
        aq[m][0] = o;
      }
      // a1: lg==0: d=32..39 (<40), partner up2, sign -; idx 32+j.
      //     lg>=1: d=40..63, partner dn0, sign +; idx 8(lg-1)+j.
      {
        const int i1 = (lg == 0) ? 32 : 8 * (lg - 1);
        const float sg1 = (lg == 0) ? -1.0f : 1.0f;
        float C[8], S[8];
#pragma unroll
        for (int j = 0; j < 8; ++j) { C[j] = cr[i1 + j]; S[j] = sr[i1 + j]; }
        bf16x8 p = (lg == 0) ? up2 : dn0;
        bf16x8 o;
#pragma unroll
        for (int j = 0; j < 8; ++j)
          o[j] = (__bf16)((((float)a1[j]) * C[j] + sg1 * ((float)p[j]) * S[j]) * qscale);
        aq[m][1] = o;
      }
      // a2 (lg<2): d=64+8lg+j (>=40), partner = lg==0 ? dn0 : dn1, sign +; idx 24+8lg+j.
      if (lg < 2) {
        const int i2 = 24 + 8 * lg;
        float C[8], S[8];
#pragma unroll
        for (int j = 0; j < 8; ++j) { C[j] = cr[i2 + j]; S[j] = sr[i2 + j]; }
        bf16x8 p = (lg == 0) ? dn0 : dn1;
        bf16x8 o;
#pragma unroll
        for (int j = 0; j < 8; ++j)
          o[j] = (__bf16)((((float)a2[j]) * C[j] + ((float)p[j]) * S[j]) * qscale);
        aq[m][2] = o;
      } else {
        aq[m][2] = z8;               // keep padding exactly zero
      }
    }
  }

  // Hoisted staging sources: wave w owns slots w*6..w*6+5 of 24 x 1KB slots.
  const char* src[6];
  size_t step[6];
#pragma unroll
  for (int i = 0; i < 6; ++i) {
    const int s = w * 6 + i;
    if (s < 12) {
      const int ks = s >> 2, n = s & 3;
      if (ks == 2 && lg >= 2) { src[i] = zpb + lane * 16; step[i] = 0; }
      else { src[i] = kbase + (size_t)(n * 16 + lr) * 160 + ks * 64 + lg * 16; step[i] = 64 * 160; }
    } else {
      const int v = s - 12, mf = v >> 1, ks2 = v & 1;
      if (mf == 5) { src[i] = zpb + lane * 16; step[i] = 0; }
      else { src[i] = vbase + (size_t)(mf * 16 + lr) * 4096 + (size_t)(ks2 * 32 + lg * 8) * 2; step[i] = 128; }
    }
  }

  auto stage = [&](int buf) {
#pragma unroll
    for (int i = 0; i < 6; ++i) {
      gload16(src[i], &smem[buf][(w * 6 + i) * 1024]);
      src[i] += step[i];
    }
  };

  f32x4 accO[5][4] = {};  // O[dh = mf*16+lg*4+j][q = w*64 + m*16 + lr]
  f32x4 accD[4] = {};     // den(q=lr) per m via ones-MFMA

  stage(0);
  asm volatile("s_waitcnt vmcnt(0)" ::: "memory");
  __builtin_amdgcn_s_barrier();
  __builtin_amdgcn_sched_barrier(0);

  for (int t = 0; t < 32; ++t) {
    const int buf = t & 1;
    if (t < 31) {
      stage(buf ^ 1);                                  // prefetch stays in flight
      asm volatile("s_waitcnt vmcnt(6)" ::: "memory"); // tile t landed; t+1 flying
    } else {
      asm volatile("s_waitcnt vmcnt(0)" ::: "memory");
    }
    __builtin_amdgcn_sched_barrier(0);
    __builtin_amdgcn_s_barrier();   // tile t visible to all waves
    __builtin_amdgcn_sched_barrier(0);

    const char* Kb = smem[buf];
    const char* Vb = smem[buf] + 12288;

    // S^T = K * Q^T for 4 Q-blocks (af fragments reused across m)
    f32x4 sc[4][4] = {};
#pragma unroll
    for (int n = 0; n < 4; ++n) {
      bf16x8 af0 = *reinterpret_cast<const bf16x8*>(Kb + (0 * 4 + n) * 1024 + lane * 16);
      bf16x8 af1 = *reinterpret_cast<const bf16x8*>(Kb + (1 * 4 + n) * 1024 + lane * 16);
      bf16x8 af2 = *reinterpret_cast<const bf16x8*>(Kb + (2 * 4 + n) * 1024 + lane * 16);
#pragma unroll
      for (int m = 0; m < 4; ++m) {
        sc[m][n] = mfma_bf16(af0, aq[m][0], sc[m][n]);
        sc[m][n] = mfma_bf16(af1, aq[m][1], sc[m][n]);
        sc[m][n] = mfma_bf16(af2, aq[m][2], sc[m][n]);
      }
    }

    // p = exp2(s); lane-local P pack (permuted k-order)
    bf16x8 bp[4][2];
#pragma unroll
    for (int m = 0; m < 4; ++m)
#pragma unroll
      for (int n = 0; n < 4; ++n) {
#pragma unroll
        for (int j = 0; j < 4; ++j)
          bp[m][n >> 1][(n & 1) * 4 + j] = (__bf16)__builtin_amdgcn_exp2f(sc[m][n][j]);
      }

    // O += P*V (V pre-permuted in global); den += ones*P on the MFMA pipe
#pragma unroll
    for (int ks2 = 0; ks2 < 2; ++ks2) {
#pragma unroll
      for (int mf = 0; mf < 5; ++mf) {
        bf16x8 av = *reinterpret_cast<const bf16x8*>(Vb + (mf * 2 + ks2) * 1024 + lane * 16);
#pragma unroll
        for (int m = 0; m < 4; ++m)
          accO[mf][m] = mfma_bf16(av, bp[m][ks2], accO[mf][m]);
      }
#pragma unroll
      for (int m = 0; m < 4; ++m)
        accD[m] = mfma_bf16(one8, bp[m][ks2], accD[m]);
    }

    __builtin_amdgcn_sched_barrier(0);
    __builtin_amdgcn_s_barrier();   // reads done -> next iter may overwrite buf^1
    __builtin_amdgcn_sched_barrier(0);
  }

  __syncthreads();

  // every lane holds den(q = w*64 + m*16 + lr) in accD[m][0]
  float rinv[4];
#pragma unroll
  for (int m = 0; m < 4; ++m) rinv[m] = 1.0f / accD[m][0];

  // O -> LDS (reuse smem: 256 rows x 160 B = 40 KB), coalesced global write
  char* sOut = smem[0];
#pragma unroll
  for (int mf = 0; mf < 5; ++mf)
#pragma unroll
    for (int m = 0; m < 4; ++m) {
      bf16x4 o4;
#pragma unroll
      for (int j = 0; j < 4; ++j) o4[j] = (__bf16)(accO[mf][m][j] * rinv[m]);
      *reinterpret_cast<bf16x4*>(sOut + (size_t)(w * 64 + m * 16 + lr) * 160 + (mf * 16 + lg * 4) * 2) = o4;
    }
  __syncthreads();

  const int b = bh >> 4, h = bh & 15;
#pragma unroll
  for (int i = 0; i < 10; ++i) {
    int c = i * 256 + tid;              // 0..2559: 256 rows x 10 slots
    int row = c / 10, slot = c - row * 10;
    int token = (qt * 256 + row) * 4 + b;
    *reinterpret_cast<bf16x8*>((char*)ow + (size_t)token * 2560 + h * 160 + slot * 16) =
        *reinterpret_cast<const bf16x8*>(sOut + row * 160 + slot * 16);
  }
}

// ---------------- launcher ----------------
extern "C" void kernel_launch(void* const* d_in, const int* in_sizes, int n_in,
                              void* d_out, int out_size, void* d_ws, size_t ws_size,
                              hipStream_t stream)
{
  const float* hidden = (const float*)d_in[0];
  const float* rot    = (const float*)d_in[1];
  const float* w1     = (const float*)d_in[2];
  const float* b1     = (const float*)d_in[3];
  const float* w2     = (const float*)d_in[4];
  const float* b2     = (const float*)d_in[5];
  float* out = (float*)d_out;

  char* ws = (char*)d_ws;
  __bf16* Xbf  = (__bf16*)(ws);                 // 8192x1280 bf16      = 20,971,520 B
  __bf16* W1bf = (__bf16*)(ws + 20971520);      // 3840x1280 bf16      =  9,830,400 B
  __bf16* W2bf = (__bf16*)(ws + 30801920);      // 1280x1280 bf16      =  3,276,800 B
  float*  ctab = (float*)(ws + 34078720);       // 2048x40 f32         =    327,680 B
  float*  stab = (float*)(ws + 34406400);       //                     =    327,680 B
  __bf16* qwp  = (__bf16*)(ws + 34734080);      // [B,H,S,80] bf16     = 20,971,520 B
  __bf16* kwp  = (__bf16*)(ws + 55705600);      // [B,H,S,80] bf16     = 20,971,520 B
  __bf16* vtwp = (__bf16*)(ws + 76677120);      // [B,H,80,S] bf16 (sigma-permuted) = 20,971,520 B
  __bf16* owp  = (__bf16*)(ws + 97648640);      // [S*B,1280] bf16     = 20,971,520 B
  float*  zp   = (float*)(ws + 118620160);      // 4KB zero page

  cast_f32_to_bf16<<<10240, 256, 0, stream>>>(hidden, Xbf, 2621440);
  cast_f32_to_bf16<<<4800, 256, 0, stream>>>(w1, W1bf, 1228800);
  cast_f32_to_bf16<<<1600, 256, 0, stream>>>(w2, W2bf, 409600);
  build_sincos<<<320, 256, 0, stream>>>(rot, ctab, stab, 81920);
  zero_fill<<<4, 256, 0, stream>>>(zp, 1024);

  gemm_qkv128<<<1920, 256, 0, stream>>>(Xbf, W1bf, b1, qwp, kwp, vtwp);

  rope_k_kernel<<<5120, 256, 0, stream>>>(kwp, ctab, stab);

  const float qscale = 1.4426950408889634f / sqrtf(80.0f);  // scale * log2(e), folded into Q
  attn_kernel<<<512, 256, 0, stream>>>(qwp, kwp, vtwp, owp, zp, ctab, stab, qscale);

  gemm_bt<1><<<640, 256, 0, stream>>>(owp, W2bf, b2, out);
}

// Round 16
// 234.669 us; speedup vs baseline: 1.0610x; 1.0610x over previous
//
#include <hip/hip_runtime.h>
#include <hip/hip_bf16.h>
#include <math.h>

typedef __bf16 bf16x4 __attribute__((ext_vector_type(4)));
typedef __bf16 bf16x8 __attribute__((ext_vector_type(8)));
typedef float  f32x4  __attribute__((ext_vector_type(4)));

#define S_LEN 2048
#define BATCH 4
#define DMODEL 1280
#define NHEAD 16
#define DHEAD 80
#define KDIM 1280

__device__ __forceinline__ f32x4 mfma_bf16(bf16x8 a, bf16x8 b, f32x4 c) {
  return __builtin_amdgcn_mfma_f32_16x16x32_bf16(a, b, c, 0, 0, 0);
}

__device__ __forceinline__ void gload16(const void* g, void* l) {
  __builtin_amdgcn_global_load_lds(
      (const __attribute__((address_space(1))) unsigned int*)g,
      (__attribute__((address_space(3))) unsigned int*)l, 16, 0, 0);
}

// ---------------- fp32 -> bf16 cast (vectorized) ----------------
__global__ void cast_f32_to_bf16(const float* __restrict__ in,
                                 __bf16* __restrict__ out, int n4) {
  int i = blockIdx.x * 256 + threadIdx.x;
  if (i >= n4) return;
  float4 v = reinterpret_cast<const float4*>(in)[i];
  bf16x4 o;
  o[0] = (__bf16)v.x; o[1] = (__bf16)v.y; o[2] = (__bf16)v.z; o[3] = (__bf16)v.w;
  reinterpret_cast<bf16x4*>(out)[i] = o;
}

// ---------------- sin/cos tables [S][40] ----------------
__global__ void build_sincos(const float* __restrict__ rot,
                             float* __restrict__ ctab, float* __restrict__ stab, int n) {
  int i = blockIdx.x * 256 + threadIdx.x;
  if (i >= n) return;
  float v = rot[i];
  ctab[i] = cosf(v);
  stab[i] = sinf(v);
}

// ---------------- zero page ----------------
__global__ void zero_fill(float* __restrict__ p, int n) {
  int i = blockIdx.x * 256 + threadIdx.x;
  if (i < n) p[i] = 0.0f;
}

// ---------------- QKV GEMM, 128x128 tile, BK=64, 4 waves, SINGLE 32KB buffer ----------------
// (unchanged from R11/R14: R9 main loop + vector-store epilogue)
__global__ __launch_bounds__(256, 4) void gemm_qkv128(
    const __bf16* __restrict__ A, const __bf16* __restrict__ Bw,
    const float* __restrict__ bias,
    __bf16* __restrict__ qw, __bf16* __restrict__ kw, __bf16* __restrict__ vtw)
{
  __shared__ __align__(1024) char smem[32768];  // A 16KB | B 16KB; reused as C-tile in epilogue
  const int tid = threadIdx.x;
  const int lane = tid & 63;
  const int w = tid >> 6;             // 0..3
  const int lr = lane & 15, lg = lane >> 4;
  const int wr = w >> 1, wc = w & 1;  // wave owns rows wr*64..+64, cols wc*64..+64

  // XCD-chunked swizzle: 8 bx-panels per XCD (A slice 2.6 MB, L2-resident)
  const int wg = blockIdx.x;          // 0..1919
  const int xcd = wg & 7, idx = wg >> 3;  // idx 0..239
  const int bx = xcd * 8 + (idx & 7);
  const int by = idx >> 3;            // 0..29
  const int r0 = bx * 128, c0 = by * 128;
  const char* asrc = (const char*)(A + (size_t)r0 * KDIM);
  const char* bsrc = (const char*)(Bw + (size_t)c0 * KDIM);

  f32x4 acc[4][4] = {};

  for (int t = 0; t < 20; ++t) {
    const size_t kb = (size_t)t * 128;  // byte offset into K dim
#pragma unroll
    for (int i = 0; i < 8; ++i) {
      const int L = i * 4096 + tid * 16;           // 0..32767
      const int r = (L & 16383) >> 7;              // row within A or B panel
      const int coff = (L & 127) ^ ((r & 7) << 4); // inverse-swizzled source
      const char* s = (L < 16384 ? asrc : bsrc) + (size_t)r * 2560 + kb + coff;
      gload16(s, &smem[L]);
    }
    __syncthreads();  // drains vmcnt+lgkm; other blocks on the CU fill the gap

#pragma unroll
    for (int kk = 0; kk < 2; ++kk) {
      bf16x8 af[4], bfr[4];
#pragma unroll
      for (int rf = 0; rf < 4; ++rf) {
        const int row = wr * 64 + rf * 16 + lr;
        af[rf] = *reinterpret_cast<const bf16x8*>(
            &smem[row * 128 + ((kk * 64 + lg * 16) ^ ((row & 7) << 4))]);
      }
#pragma unroll
      for (int cf = 0; cf < 4; ++cf) {
        const int row = wc * 64 + cf * 16 + lr;
        bfr[cf] = *reinterpret_cast<const bf16x8*>(
            &smem[16384 + row * 128 + ((kk * 64 + lg * 16) ^ ((row & 7) << 4))]);
      }
#pragma unroll
      for (int rf = 0; rf < 4; ++rf)
#pragma unroll
        for (int cf = 0; cf < 4; ++cf)
          acc[rf][cf] = mfma_bf16(af[rf], bfr[cf], acc[rf][cf]);
    }
    __syncthreads();  // reads done -> next stage may overwrite
  }

  // ---- epilogue ----
  float biasr[4];
#pragma unroll
  for (int cf = 0; cf < 4; ++cf) biasr[cf] = bias[c0 + wc * 64 + cf * 16 + lr];

  // stage C-tile to LDS: row-major [128 rows][128 cols] bf16, col-XOR swizzle
#pragma unroll
  for (int cf = 0; cf < 4; ++cf) {
    const int col = wc * 64 + cf * 16 + lr;
#pragma unroll
    for (int rf = 0; rf < 4; ++rf)
#pragma unroll
      for (int j = 0; j < 4; ++j) {
        const int row = wr * 64 + rf * 16 + lg * 4 + j;
        *reinterpret_cast<__bf16*>(
            &smem[row * 256 + ((col ^ ((row & 7) << 3)) << 1)]) =
            (__bf16)(acc[rf][cf][j] + biasr[cf]);
      }
  }
  __syncthreads();

  const int which = c0 / DMODEL;          // 0=q, 1=k, 2=v (block-uniform)
  const int ee0 = c0 - which * DMODEL;    // channel base within {q,k,v}

  if (which < 2) {
    __bf16* dst = (which == 0) ? qw : kw;
#pragma unroll
    for (int i = 0; i < 8; ++i) {
      const int cid = i * 256 + tid;      // 0..2047
      const int row = cid >> 4, slot = cid & 15;
      bf16x8 v = *reinterpret_cast<const bf16x8*>(
          &smem[row * 256 + ((slot ^ (row & 7)) << 4)]);
      const int tr = r0 + row;
      const int b = tr & 3, stok = tr >> 2;
      const int ee = ee0 + slot * 8;      // 8-aligned; 8|80 -> never straddles a head
      const int h = ee / DHEAD, dh = ee - h * DHEAD;
      *reinterpret_cast<bf16x8*>(
          &dst[((size_t)(b * NHEAD + h) * S_LEN + stok) * DHEAD + dh]) = v;
    }
  } else {
    const int s0 = r0 >> 2;               // 32-aligned token/4 base
#pragma unroll
    for (int i = 0; i < 8; ++i) {
      const int cid = i * 256 + tid;      // 0..2047
      const int col = cid >> 4;           // channel within tile, 0..127
      const int b = (cid >> 2) & 3, spblk = cid & 3;
      bf16x8 v;
#pragma unroll
      for (int k = 0; k < 8; ++k) {
        const int spl = spblk * 8 + k;
        // inverse sigma: s = (sp&3) | ((sp&24)>>1) | ((sp&4)<<2)
        const int sl = (spl & 3) | ((spl & 24) >> 1) | ((spl & 4) << 2);
        const int row = sl * 4 + b;
        v[k] = *reinterpret_cast<const __bf16*>(
            &smem[row * 256 + ((col ^ ((row & 7) << 3)) << 1)]);
      }
      const int ee = ee0 + col;
      const int h = ee / DHEAD, dh = ee - h * DHEAD;
      *reinterpret_cast<bf16x8*>(
          &vtw[((size_t)(b * NHEAD + h) * DHEAD + dh) * S_LEN + s0 + spblk * 8]) = v;
    }
  }
}

// ---------------- out-proj GEMM, 128x128, SINGLE 32KB buffer (m97 regime, R9-proven) ----------------
__global__ __launch_bounds__(256, 4) void gemm_out128(
    const __bf16* __restrict__ A, const __bf16* __restrict__ Bw,
    const float* __restrict__ bias, float* __restrict__ outf)
{
  __shared__ __align__(1024) char smem[32768];  // A 16KB | B 16KB
  const int tid = threadIdx.x;
  const int lane = tid & 63;
  const int w = tid >> 6;
  const int lr = lane & 15, lg = lane >> 4;
  const int wr = w >> 1, wc = w & 1;

  const int wg = blockIdx.x;          // 0..639
  const int xcd = wg & 7, idx = wg >> 3;  // idx 0..79
  const int bx = xcd * 8 + (idx & 7);
  const int by = idx >> 3;            // 0..9
  const int r0 = bx * 128, c0 = by * 128;
  const char* asrc = (const char*)(A + (size_t)r0 * KDIM);
  const char* bsrc = (const char*)(Bw + (size_t)c0 * KDIM);

  f32x4 acc[4][4] = {};

  for (int t = 0; t < 20; ++t) {
    const size_t kb = (size_t)t * 128;
#pragma unroll
    for (int i = 0; i < 8; ++i) {
      const int L = i * 4096 + tid * 16;
      const int r = (L & 16383) >> 7;
      const int coff = (L & 127) ^ ((r & 7) << 4);
      const char* s = (L < 16384 ? asrc : bsrc) + (size_t)r * 2560 + kb + coff;
      gload16(s, &smem[L]);
    }
    __syncthreads();

#pragma unroll
    for (int kk = 0; kk < 2; ++kk) {
      bf16x8 af[4], bfr[4];
#pragma unroll
      for (int rf = 0; rf < 4; ++rf) {
        const int row = wr * 64 + rf * 16 + lr;
        af[rf] = *reinterpret_cast<const bf16x8*>(
            &smem[row * 128 + ((kk * 64 + lg * 16) ^ ((row & 7) << 4))]);
      }
#pragma unroll
      for (int cf = 0; cf < 4; ++cf) {
        const int row = wc * 64 + cf * 16 + lr;
        bfr[cf] = *reinterpret_cast<const bf16x8*>(
            &smem[16384 + row * 128 + ((kk * 64 + lg * 16) ^ ((row & 7) << 4))]);
      }
#pragma unroll
      for (int rf = 0; rf < 4; ++rf)
#pragma unroll
        for (int cf = 0; cf < 4; ++cf)
          acc[rf][cf] = mfma_bf16(af[rf], bfr[cf], acc[rf][cf]);
    }
    __syncthreads();
  }

  float biasr[4];
#pragma unroll
  for (int cf = 0; cf < 4; ++cf) biasr[cf] = bias[c0 + wc * 64 + cf * 16 + lr];

#pragma unroll
  for (int rf = 0; rf < 4; ++rf)
#pragma unroll
    for (int cf = 0; cf < 4; ++cf) {
      const int c = c0 + wc * 64 + cf * 16 + lr;
#pragma unroll
      for (int j = 0; j < 4; ++j) {
        const int r = r0 + wr * 64 + rf * 16 + lg * 4 + j;
        outf[(size_t)r * DMODEL + c] = acc[rf][cf][j] + biasr[cf];
      }
    }
}

// ---------------- RoPE in-place on q,k; q additionally pre-scaled by scale*log2e ----------------
__global__ void rope_kernel(__bf16* __restrict__ qw, __bf16* __restrict__ kw,
                            const float* __restrict__ ctab, const float* __restrict__ stab,
                            float qscale)
{
  int idx = blockIdx.x * 256 + threadIdx.x;  // 2*64*2048*10 threads
  const int j = idx % 10;
  int rest = idx / 10;
  const int s = rest & (S_LEN - 1);
  rest >>= 11;
  const int bh = rest & 63;
  const int isk = rest >> 6;
  __bf16* base = (isk ? kw : qw) + ((size_t)bh * S_LEN + s) * DHEAD;
  const float4 c4 = *reinterpret_cast<const float4*>(ctab + s * 40 + j * 4);
  const float4 s4 = *reinterpret_cast<const float4*>(stab + s * 40 + j * 4);
  bf16x4 a = *reinterpret_cast<bf16x4*>(base + j * 4);
  bf16x4 b = *reinterpret_cast<bf16x4*>(base + 40 + j * 4);
  const float m = isk ? 1.0f : qscale;
  const float cc[4] = {c4.x, c4.y, c4.z, c4.w};
  const float ss[4] = {s4.x, s4.y, s4.z, s4.w};
#pragma unroll
  for (int t = 0; t < 4; ++t) {
    float fa = (float)a[t], fb = (float)b[t];
    a[t] = (__bf16)((fa * cc[t] - fb * ss[t]) * m);
    b[t] = (__bf16)((fb * cc[t] + fa * ss[t]) * m);
  }
  *reinterpret_cast<bf16x4*>(base + j * 4) = a;
  *reinterpret_cast<bf16x4*>(base + 40 + j * 4) = b;
}

// ---------------- attention v10 = R14 v8 + T5 setprio around MFMA clusters ----------------
__global__ __launch_bounds__(256, 2) void attn_kernel(
    const __bf16* __restrict__ qw, const __bf16* __restrict__ kw,
    const __bf16* __restrict__ vtw, __bf16* __restrict__ ow,
    const float* __restrict__ zp)
{
  __shared__ __align__(1024) char smem[2][24576];  // [buf][K 12KB | V 10KB | 2KB trash]

  const int tid = threadIdx.x;
  const int lane = tid & 63;
  const int w = tid >> 6;             // 0..3
  const int lr = lane & 15, lg = lane >> 4;

  // XCD-aware mapping: all 8 q-tiles of one bh on one XCD
  const int wg = blockIdx.x;          // 0..511
  const int local = wg >> 3;          // 0..63
  const int bh = (wg & 7) * 8 + (local >> 3);
  const int qt = local & 7;

  const char* qbase = (const char*)(qw + ((size_t)bh * S_LEN + qt * 256) * DHEAD);
  const char* kbase = (const char*)(kw + (size_t)bh * S_LEN * DHEAD);
  const char* vbase = (const char*)(vtw + (size_t)bh * DHEAD * S_LEN);
  const char* zpb = (const char*)zp;

  bf16x8 z8, one8;
#pragma unroll
  for (int i = 0; i < 8; ++i) { z8[i] = (__bf16)0.0f; one8[i] = (__bf16)1.0f; }

  // Q fragments (B-operand): q = w*64 + m*16 + lr, d-chunks {0..31,32..63,64..79+pad}
  bf16x8 aq[4][3];
#pragma unroll
  for (int m = 0; m < 4; ++m) {
    const char* rp = qbase + (size_t)(w * 64 + m * 16 + lr) * 160;
    aq[m][0] = *reinterpret_cast<const bf16x8*>(rp + lg * 16);
    aq[m][1] = *reinterpret_cast<const bf16x8*>(rp + 64 + lg * 16);
    aq[m][2] = (lg < 2) ? *reinterpret_cast<const bf16x8*>(rp + 128 + lg * 16) : z8;
  }

  // Hoisted staging sources: wave w owns slots w*6..w*6+5 of 24 x 1KB slots.
  const char* src[6];
  size_t step[6];
#pragma unroll
  for (int i = 0; i < 6; ++i) {
    const int s = w * 6 + i;
    if (s < 12) {
      const int ks = s >> 2, n = s & 3;
      if (ks == 2 && lg >= 2) { src[i] = zpb + lane * 16; step[i] = 0; }
      else { src[i] = kbase + (size_t)(n * 16 + lr) * 160 + ks * 64 + lg * 16; step[i] = 64 * 160; }
    } else {
      const int v = s - 12, mf = v >> 1, ks2 = v & 1;
      if (mf == 5) { src[i] = zpb + lane * 16; step[i] = 0; }
      else { src[i] = vbase + (size_t)(mf * 16 + lr) * 4096 + (size_t)(ks2 * 32 + lg * 8) * 2; step[i] = 128; }
    }
  }

  auto stage = [&](int buf) {
#pragma unroll
    for (int i = 0; i < 6; ++i) {
      gload16(src[i], &smem[buf][(w * 6 + i) * 1024]);
      src[i] += step[i];
    }
  };

  f32x4 accO[5][4] = {};  // O[dh = mf*16+lg*4+j][q = w*64 + m*16 + lr]
  f32x4 accD[4] = {};     // den(q=lr) per m via ones-MFMA

  stage(0);
  asm volatile("s_waitcnt vmcnt(0)" ::: "memory");
  __builtin_amdgcn_s_barrier();
  __builtin_amdgcn_sched_barrier(0);

  for (int t = 0; t < 32; ++t) {
    const int buf = t & 1;
    if (t < 31) {
      stage(buf ^ 1);                                  // prefetch stays in flight
      asm volatile("s_waitcnt vmcnt(6)" ::: "memory"); // tile t landed; t+1 flying
    } else {
      asm volatile("s_waitcnt vmcnt(0)" ::: "memory");
    }
    __builtin_amdgcn_sched_barrier(0);
    __builtin_amdgcn_s_barrier();   // tile t visible to all waves
    __builtin_amdgcn_sched_barrier(0);

    const char* Kb = smem[buf];
    const char* Vb = smem[buf] + 12288;

    // S^T = K * Q^T for 4 Q-blocks (af fragments reused across m)
    f32x4 sc[4][4] = {};
    __builtin_amdgcn_s_setprio(1);
#pragma unroll
    for (int n = 0; n < 4; ++n) {
      bf16x8 af0 = *reinterpret_cast<const bf16x8*>(Kb + (0 * 4 + n) * 1024 + lane * 16);
      bf16x8 af1 = *reinterpret_cast<const bf16x8*>(Kb + (1 * 4 + n) * 1024 + lane * 16);
      bf16x8 af2 = *reinterpret_cast<const bf16x8*>(Kb + (2 * 4 + n) * 1024 + lane * 16);
#pragma unroll
      for (int m = 0; m < 4; ++m) {
        sc[m][n] = mfma_bf16(af0, aq[m][0], sc[m][n]);
        sc[m][n] = mfma_bf16(af1, aq[m][1], sc[m][n]);
        sc[m][n] = mfma_bf16(af2, aq[m][2], sc[m][n]);
      }
    }
    __builtin_amdgcn_s_setprio(0);

    // p = exp2(s); lane-local P pack (permuted k-order)
    bf16x8 bp[4][2];
#pragma unroll
    for (int m = 0; m < 4; ++m)
#pragma unroll
      for (int n = 0; n < 4; ++n) {
#pragma unroll
        for (int j = 0; j < 4; ++j)
          bp[m][n >> 1][(n & 1) * 4 + j] = (__bf16)__builtin_amdgcn_exp2f(sc[m][n][j]);
      }

    // O += P*V (V pre-permuted in global); den += ones*P on the MFMA pipe
    __builtin_amdgcn_s_setprio(1);
#pragma unroll
    for (int ks2 = 0; ks2 < 2; ++ks2) {
#pragma unroll
      for (int mf = 0; mf < 5; ++mf) {
        bf16x8 av = *reinterpret_cast<const bf16x8*>(Vb + (mf * 2 + ks2) * 1024 + lane * 16);
#pragma unroll
        for (int m = 0; m < 4; ++m)
          accO[mf][m] = mfma_bf16(av, bp[m][ks2], accO[mf][m]);
      }
#pragma unroll
      for (int m = 0; m < 4; ++m)
        accD[m] = mfma_bf16(one8, bp[m][ks2], accD[m]);
    }
    __builtin_amdgcn_s_setprio(0);

    __builtin_amdgcn_sched_barrier(0);
    __builtin_amdgcn_s_barrier();   // reads done -> next iter may overwrite buf^1
    __builtin_amdgcn_sched_barrier(0);
  }

  __syncthreads();

  // every lane holds den(q = w*64 + m*16 + lr) in accD[m][0]
  float rinv[4];
#pragma unroll
  for (int m = 0; m < 4; ++m) rinv[m] = 1.0f / accD[m][0];

  // O -> LDS (reuse smem: 256 rows x 160 B = 40 KB), coalesced global write
  char* sOut = smem[0];
#pragma unroll
  for (int mf = 0; mf < 5; ++mf)
#pragma unroll
    for (int m = 0; m < 4; ++m) {
      bf16x4 o4;
#pragma unroll
      for (int j = 0; j < 4; ++j) o4[j] = (__bf16)(accO[mf][m][j] * rinv[m]);
      *reinterpret_cast<bf16x4*>(sOut + (size_t)(w * 64 + m * 16 + lr) * 160 + (mf * 16 + lg * 4) * 2) = o4;
    }
  __syncthreads();

  const int b = bh >> 4, h = bh & 15;
#pragma unroll
  for (int i = 0; i < 10; ++i) {
    int c = i * 256 + tid;              // 0..2559: 256 rows x 10 slots
    int row = c / 10, slot = c - row * 10;
    int token = (qt * 256 + row) * 4 + b;
    *reinterpret_cast<bf16x8*>((char*)ow + (size_t)token * 2560 + h * 160 + slot * 16) =
        *reinterpret_cast<const bf16x8*>(sOut + row * 160 + slot * 16);
  }
}

// ---------------- launcher ----------------
extern "C" void kernel_launch(void* const* d_in, const int* in_sizes, int n_in,
                              void* d_out, int out_size, void* d_ws, size_t ws_size,
                              hipStream_t stream)
{
  const float* hidden = (const float*)d_in[0];
  const float* rot    = (const float*)d_in[1];
  const float* w1     = (const float*)d_in[2];
  const float* b1     = (const float*)d_in[3];
  const float* w2     = (const float*)d_in[4];
  const float* b2     = (const float*)d_in[5];
  float* out = (float*)d_out;

  char* ws = (char*)d_ws;
  __bf16* Xbf  = (__bf16*)(ws);                 // 8192x1280 bf16      = 20,971,520 B
  __bf16* W1bf = (__bf16*)(ws + 20971520);      // 3840x1280 bf16      =  9,830,400 B
  __bf16* W2bf = (__bf16*)(ws + 30801920);      // 1280x1280 bf16      =  3,276,800 B
  float*  ctab = (float*)(ws + 34078720);       // 2048x40 f32         =    327,680 B
  float*  stab = (float*)(ws + 34406400);       //                     =    327,680 B
  __bf16* qwp  = (__bf16*)(ws + 34734080);      // [B,H,S,80] bf16     = 20,971,520 B
  __bf16* kwp  = (__bf16*)(ws + 55705600);      // [B,H,S,80] bf16     = 20,971,520 B
  __bf16* vtwp = (__bf16*)(ws + 76677120);      // [B,H,80,S] bf16 (sigma-permuted) = 20,971,520 B
  __bf16* owp  = (__bf16*)(ws + 97648640);      // [S*B,1280] bf16     = 20,971,520 B
  float*  zp   = (float*)(ws + 118620160);      // 4KB zero page

  cast_f32_to_bf16<<<10240, 256, 0, stream>>>(hidden, Xbf, 2621440);
  cast_f32_to_bf16<<<4800, 256, 0, stream>>>(w1, W1bf, 1228800);
  cast_f32_to_bf16<<<1600, 256, 0, stream>>>(w2, W2bf, 409600);
  build_sincos<<<320, 256, 0, stream>>>(rot, ctab, stab, 81920);
  zero_fill<<<4, 256, 0, stream>>>(zp, 1024);

  gemm_qkv128<<<1920, 256, 0, stream>>>(Xbf, W1bf, b1, qwp, kwp, vtwp);

  const float qscale = 1.4426950408889634f / sqrtf(80.0f);  // scale * log2(e), folded into Q
  rope_kernel<<<10240, 256, 0, stream>>>(qwp, kwp, ctab, stab, qscale);

  attn_kernel<<<512, 256, 0, stream>>>(qwp, kwp, vtwp, owp, zp);

  gemm_out128<<<640, 256, 0, stream>>>(owp, W2bf, b2, out);
}

// Round 17
// 233.094 us; speedup vs baseline: 1.0681x; 1.0068x over previous
//
#include <hip/hip_runtime.h>
#include <hip/hip_bf16.h>
#include <math.h>

typedef __bf16 bf16x4 __attribute__((ext_vector_type(4)));
typedef __bf16 bf16x8 __attribute__((ext_vector_type(8)));
typedef float  f32x4  __attribute__((ext_vector_type(4)));

#define S_LEN 2048
#define BATCH 4
#define DMODEL 1280
#define NHEAD 16
#define DHEAD 80
#define KDIM 1280

__device__ __forceinline__ f32x4 mfma_bf16(bf16x8 a, bf16x8 b, f32x4 c) {
  return __builtin_amdgcn_mfma_f32_16x16x32_bf16(a, b, c, 0, 0, 0);
}

__device__ __forceinline__ void gload16(const void* g, void* l) {
  __builtin_amdgcn_global_load_lds(
      (const __attribute__((address_space(1))) unsigned int*)g,
      (__attribute__((address_space(3))) unsigned int*)l, 16, 0, 0);
}

// ---------------- merged prep: 3 casts + sincos table + zero page, ONE launch ----------------
__global__ void prep_kernel(const float* __restrict__ hidden, const float* __restrict__ w1,
                            const float* __restrict__ w2, const float* __restrict__ rot,
                            __bf16* __restrict__ Xbf, __bf16* __restrict__ W1bf,
                            __bf16* __restrict__ W2bf, float* __restrict__ ctab,
                            float* __restrict__ stab, float* __restrict__ zp)
{
  int i = blockIdx.x * 256 + threadIdx.x;
  if (i < 2621440) {
    float4 v = reinterpret_cast<const float4*>(hidden)[i];
    bf16x4 o;
    o[0] = (__bf16)v.x; o[1] = (__bf16)v.y; o[2] = (__bf16)v.z; o[3] = (__bf16)v.w;
    reinterpret_cast<bf16x4*>(Xbf)[i] = o;
    return;
  }
  i -= 2621440;
  if (i < 1228800) {
    float4 v = reinterpret_cast<const float4*>(w1)[i];
    bf16x4 o;
    o[0] = (__bf16)v.x; o[1] = (__bf16)v.y; o[2] = (__bf16)v.z; o[3] = (__bf16)v.w;
    reinterpret_cast<bf16x4*>(W1bf)[i] = o;
    return;
  }
  i -= 1228800;
  if (i < 409600) {
    float4 v = reinterpret_cast<const float4*>(w2)[i];
    bf16x4 o;
    o[0] = (__bf16)v.x; o[1] = (__bf16)v.y; o[2] = (__bf16)v.z; o[3] = (__bf16)v.w;
    reinterpret_cast<bf16x4*>(W2bf)[i] = o;
    return;
  }
  i -= 409600;
  if (i < 81920) {
    float v = rot[i];
    ctab[i] = cosf(v);
    stab[i] = sinf(v);
    return;
  }
  i -= 81920;
  if (i < 1024) zp[i] = 0.0f;
}

// ---------------- QKV GEMM, 128x128 tile, BK=64, 4 waves, SINGLE 32KB buffer ----------------
// (unchanged from R16: R9 main loop + vector-store epilogue)
__global__ __launch_bounds__(256, 4) void gemm_qkv128(
    const __bf16* __restrict__ A, const __bf16* __restrict__ Bw,
    const float* __restrict__ bias,
    __bf16* __restrict__ qw, __bf16* __restrict__ kw, __bf16* __restrict__ vtw)
{
  __shared__ __align__(1024) char smem[32768];  // A 16KB | B 16KB; reused as C-tile in epilogue
  const int tid = threadIdx.x;
  const int lane = tid & 63;
  const int w = tid >> 6;             // 0..3
  const int lr = lane & 15, lg = lane >> 4;
  const int wr = w >> 1, wc = w & 1;  // wave owns rows wr*64..+64, cols wc*64..+64

  // XCD-chunked swizzle: 8 bx-panels per XCD (A slice 2.6 MB, L2-resident)
  const int wg = blockIdx.x;          // 0..1919
  const int xcd = wg & 7, idx = wg >> 3;  // idx 0..239
  const int bx = xcd * 8 + (idx & 7);
  const int by = idx >> 3;            // 0..29
  const int r0 = bx * 128, c0 = by * 128;
  const char* asrc = (const char*)(A + (size_t)r0 * KDIM);
  const char* bsrc = (const char*)(Bw + (size_t)c0 * KDIM);

  f32x4 acc[4][4] = {};

  for (int t = 0; t < 20; ++t) {
    const size_t kb = (size_t)t * 128;  // byte offset into K dim
#pragma unroll
    for (int i = 0; i < 8; ++i) {
      const int L = i * 4096 + tid * 16;           // 0..32767
      const int r = (L & 16383) >> 7;              // row within A or B panel
      const int coff = (L & 127) ^ ((r & 7) << 4); // inverse-swizzled source
      const char* s = (L < 16384 ? asrc : bsrc) + (size_t)r * 2560 + kb + coff;
      gload16(s, &smem[L]);
    }
    __syncthreads();  // drains vmcnt+lgkm; other blocks on the CU fill the gap

#pragma unroll
    for (int kk = 0; kk < 2; ++kk) {
      bf16x8 af[4], bfr[4];
#pragma unroll
      for (int rf = 0; rf < 4; ++rf) {
        const int row = wr * 64 + rf * 16 + lr;
        af[rf] = *reinterpret_cast<const bf16x8*>(
            &smem[row * 128 + ((kk * 64 + lg * 16) ^ ((row & 7) << 4))]);
      }
#pragma unroll
      for (int cf = 0; cf < 4; ++cf) {
        const int row = wc * 64 + cf * 16 + lr;
        bfr[cf] = *reinterpret_cast<const bf16x8*>(
            &smem[16384 + row * 128 + ((kk * 64 + lg * 16) ^ ((row & 7) << 4))]);
      }
#pragma unroll
      for (int rf = 0; rf < 4; ++rf)
#pragma unroll
        for (int cf = 0; cf < 4; ++cf)
          acc[rf][cf] = mfma_bf16(af[rf], bfr[cf], acc[rf][cf]);
    }
    __syncthreads();  // reads done -> next stage may overwrite
  }

  // ---- epilogue ----
  float biasr[4];
#pragma unroll
  for (int cf = 0; cf < 4; ++cf) biasr[cf] = bias[c0 + wc * 64 + cf * 16 + lr];

  // stage C-tile to LDS: row-major [128 rows][128 cols] bf16, col-XOR swizzle
#pragma unroll
  for (int cf = 0; cf < 4; ++cf) {
    const int col = wc * 64 + cf * 16 + lr;
#pragma unroll
    for (int rf = 0; rf < 4; ++rf)
#pragma unroll
      for (int j = 0; j < 4; ++j) {
        const int row = wr * 64 + rf * 16 + lg * 4 + j;
        *reinterpret_cast<__bf16*>(
            &smem[row * 256 + ((col ^ ((row & 7) << 3)) << 1)]) =
            (__bf16)(acc[rf][cf][j] + biasr[cf]);
      }
  }
  __syncthreads();

  const int which = c0 / DMODEL;          // 0=q, 1=k, 2=v (block-uniform)
  const int ee0 = c0 - which * DMODEL;    // channel base within {q,k,v}

  if (which < 2) {
    __bf16* dst = (which == 0) ? qw : kw;
#pragma unroll
    for (int i = 0; i < 8; ++i) {
      const int cid = i * 256 + tid;      // 0..2047
      const int row = cid >> 4, slot = cid & 15;
      bf16x8 v = *reinterpret_cast<const bf16x8*>(
          &smem[row * 256 + ((slot ^ (row & 7)) << 4)]);
      const int tr = r0 + row;
      const int b = tr & 3, stok = tr >> 2;
      const int ee = ee0 + slot * 8;      // 8-aligned; 8|80 -> never straddles a head
      const int h = ee / DHEAD, dh = ee - h * DHEAD;
      *reinterpret_cast<bf16x8*>(
          &dst[((size_t)(b * NHEAD + h) * S_LEN + stok) * DHEAD + dh]) = v;
    }
  } else {
    const int s0 = r0 >> 2;               // 32-aligned token/4 base
#pragma unroll
    for (int i = 0; i < 8; ++i) {
      const int cid = i * 256 + tid;      // 0..2047
      const int col = cid >> 4;           // channel within tile, 0..127
      const int b = (cid >> 2) & 3, spblk = cid & 3;
      bf16x8 v;
#pragma unroll
      for (int k = 0; k < 8; ++k) {
        const int spl = spblk * 8 + k;
        // inverse sigma: s = (sp&3) | ((sp&24)>>1) | ((sp&4)<<2)
        const int sl = (spl & 3) | ((spl & 24) >> 1) | ((spl & 4) << 2);
        const int row = sl * 4 + b;
        v[k] = *reinterpret_cast<const __bf16*>(
            &smem[row * 256 + ((col ^ ((row & 7) << 3)) << 1)]);
      }
      const int ee = ee0 + col;
      const int h = ee / DHEAD, dh = ee - h * DHEAD;
      *reinterpret_cast<bf16x8*>(
          &vtw[((size_t)(b * NHEAD + h) * DHEAD + dh) * S_LEN + s0 + spblk * 8]) = v;
    }
  }
}

// ---------------- out-proj GEMM, 128x128, SINGLE 32KB buffer (unchanged from R16) ----------------
__global__ __launch_bounds__(256, 4) void gemm_out128(
    const __bf16* __restrict__ A, const __bf16* __restrict__ Bw,
    const float* __restrict__ bias, float* __restrict__ outf)
{
  __shared__ __align__(1024) char smem[32768];  // A 16KB | B 16KB
  const int tid = threadIdx.x;
  const int lane = tid & 63;
  const int w = tid >> 6;
  const int lr = lane & 15, lg = lane >> 4;
  const int wr = w >> 1, wc = w & 1;

  const int wg = blockIdx.x;          // 0..639
  const int xcd = wg & 7, idx = wg >> 3;  // idx 0..79
  const int bx = xcd * 8 + (idx & 7);
  const int by = idx >> 3;            // 0..9
  const int r0 = bx * 128, c0 = by * 128;
  const char* asrc = (const char*)(A + (size_t)r0 * KDIM);
  const char* bsrc = (const char*)(Bw + (size_t)c0 * KDIM);

  f32x4 acc[4][4] = {};

  for (int t = 0; t < 20; ++t) {
    const size_t kb = (size_t)t * 128;
#pragma unroll
    for (int i = 0; i < 8; ++i) {
      const int L = i * 4096 + tid * 16;
      const int r = (L & 16383) >> 7;
      const int coff = (L & 127) ^ ((r & 7) << 4);
      const char* s = (L < 16384 ? asrc : bsrc) + (size_t)r * 2560 + kb + coff;
      gload16(s, &smem[L]);
    }
    __syncthreads();

#pragma unroll
    for (int kk = 0; kk < 2; ++kk) {
      bf16x8 af[4], bfr[4];
#pragma unroll
      for (int rf = 0; rf < 4; ++rf) {
        const int row = wr * 64 + rf * 16 + lr;
        af[rf] = *reinterpret_cast<const bf16x8*>(
            &smem[row * 128 + ((kk * 64 + lg * 16) ^ ((row & 7) << 4))]);
      }
#pragma unroll
      for (int cf = 0; cf < 4; ++cf) {
        const int row = wc * 64 + cf * 16 + lr;
        bfr[cf] = *reinterpret_cast<const bf16x8*>(
            &smem[16384 + row * 128 + ((kk * 64 + lg * 16) ^ ((row & 7) << 4))]);
      }
#pragma unroll
      for (int rf = 0; rf < 4; ++rf)
#pragma unroll
        for (int cf = 0; cf < 4; ++cf)
          acc[rf][cf] = mfma_bf16(af[rf], bfr[cf], acc[rf][cf]);
    }
    __syncthreads();
  }

  float biasr[4];
#pragma unroll
  for (int cf = 0; cf < 4; ++cf) biasr[cf] = bias[c0 + wc * 64 + cf * 16 + lr];

#pragma unroll
  for (int rf = 0; rf < 4; ++rf)
#pragma unroll
    for (int cf = 0; cf < 4; ++cf) {
      const int c = c0 + wc * 64 + cf * 16 + lr;
#pragma unroll
      for (int j = 0; j < 4; ++j) {
        const int r = r0 + wr * 64 + rf * 16 + lg * 4 + j;
        outf[(size_t)r * DMODEL + c] = acc[rf][cf][j] + biasr[cf];
      }
    }
}

// ---------------- RoPE in-place on q,k; q additionally pre-scaled by scale*log2e ----------------
__global__ void rope_kernel(__bf16* __restrict__ qw, __bf16* __restrict__ kw,
                            const float* __restrict__ ctab, const float* __restrict__ stab,
                            float qscale)
{
  int idx = blockIdx.x * 256 + threadIdx.x;  // 2*64*2048*10 threads
  const int j = idx % 10;
  int rest = idx / 10;
  const int s = rest & (S_LEN - 1);
  rest >>= 11;
  const int bh = rest & 63;
  const int isk = rest >> 6;
  __bf16* base = (isk ? kw : qw) + ((size_t)bh * S_LEN + s) * DHEAD;
  const float4 c4 = *reinterpret_cast<const float4*>(ctab + s * 40 + j * 4);
  const float4 s4 = *reinterpret_cast<const float4*>(stab + s * 40 + j * 4);
  bf16x4 a = *reinterpret_cast<bf16x4*>(base + j * 4);
  bf16x4 b = *reinterpret_cast<bf16x4*>(base + 40 + j * 4);
  const float m = isk ? 1.0f : qscale;
  const float cc[4] = {c4.x, c4.y, c4.z, c4.w};
  const float ss[4] = {s4.x, s4.y, s4.z, s4.w};
#pragma unroll
  for (int t = 0; t < 4; ++t) {
    float fa = (float)a[t], fb = (float)b[t];
    a[t] = (__bf16)((fa * cc[t] - fb * ss[t]) * m);
    b[t] = (__bf16)((fb * cc[t] + fa * ss[t]) * m);
  }
  *reinterpret_cast<bf16x4*>(base + j * 4) = a;
  *reinterpret_cast<bf16x4*>(base + 40 + j * 4) = b;
}

// ---------------- attention v11 = v10 + m-interleaved QK/exp (serial-chain break) ----------------
// All 12 K fragments promoted to regs; QK restructured m-major so exp/pack(m) overlaps
// QK(m+1)'s independent MFMA stream. Sync/staging/LDS byte-identical to v10. VGPR
// headroom is free: occupancy is grid-limited (512 blocks = 2/CU).
__global__ __launch_bounds__(256, 2) void attn_kernel(
    const __bf16* __restrict__ qw, const __bf16* __restrict__ kw,
    const __bf16* __restrict__ vtw, __bf16* __restrict__ ow,
    const float* __restrict__ zp)
{
  __shared__ __align__(1024) char smem[2][24576];  // [buf][K 12KB | V 10KB | 2KB trash]

  const int tid = threadIdx.x;
  const int lane = tid & 63;
  const int w = tid >> 6;             // 0..3
  const int lr = lane & 15, lg = lane >> 4;

  // XCD-aware mapping: all 8 q-tiles of one bh on one XCD
  const int wg = blockIdx.x;          // 0..511
  const int local = wg >> 3;          // 0..63
  const int bh = (wg & 7) * 8 + (local >> 3);
  const int qt = local & 7;

  const char* qbase = (const char*)(qw + ((size_t)bh * S_LEN + qt * 256) * DHEAD);
  const char* kbase = (const char*)(kw + (size_t)bh * S_LEN * DHEAD);
  const char* vbase = (const char*)(vtw + (size_t)bh * DHEAD * S_LEN);
  const char* zpb = (const char*)zp;

  bf16x8 z8, one8;
#pragma unroll
  for (int i = 0; i < 8; ++i) { z8[i] = (__bf16)0.0f; one8[i] = (__bf16)1.0f; }

  // Q fragments (B-operand): q = w*64 + m*16 + lr, d-chunks {0..31,32..63,64..79+pad}
  bf16x8 aq[4][3];
#pragma unroll
  for (int m = 0; m < 4; ++m) {
    const char* rp = qbase + (size_t)(w * 64 + m * 16 + lr) * 160;
    aq[m][0] = *reinterpret_cast<const bf16x8*>(rp + lg * 16);
    aq[m][1] = *reinterpret_cast<const bf16x8*>(rp + 64 + lg * 16);
    aq[m][2] = (lg < 2) ? *reinterpret_cast<const bf16x8*>(rp + 128 + lg * 16) : z8;
  }

  // Hoisted staging sources: wave w owns slots w*6..w*6+5 of 24 x 1KB slots.
  const char* src[6];
  size_t step[6];
#pragma unroll
  for (int i = 0; i < 6; ++i) {
    const int s = w * 6 + i;
    if (s < 12) {
      const int ks = s >> 2, n = s & 3;
      if (ks == 2 && lg >= 2) { src[i] = zpb + lane * 16; step[i] = 0; }
      else { src[i] = kbase + (size_t)(n * 16 + lr) * 160 + ks * 64 + lg * 16; step[i] = 64 * 160; }
    } else {
      const int v = s - 12, mf = v >> 1, ks2 = v & 1;
      if (mf == 5) { src[i] = zpb + lane * 16; step[i] = 0; }
      else { src[i] = vbase + (size_t)(mf * 16 + lr) * 4096 + (size_t)(ks2 * 32 + lg * 8) * 2; step[i] = 128; }
    }
  }

  auto stage = [&](int buf) {
#pragma unroll
    for (int i = 0; i < 6; ++i) {
      gload16(src[i], &smem[buf][(w * 6 + i) * 1024]);
      src[i] += step[i];
    }
  };

  f32x4 accO[5][4] = {};  // O[dh = mf*16+lg*4+j][q = w*64 + m*16 + lr]
  f32x4 accD[4] = {};     // den(q=lr) per m via ones-MFMA

  stage(0);
  asm volatile("s_waitcnt vmcnt(0)" ::: "memory");
  __builtin_amdgcn_s_barrier();
  __builtin_amdgcn_sched_barrier(0);

  for (int t = 0; t < 32; ++t) {
    const int buf = t & 1;
    if (t < 31) {
      stage(buf ^ 1);                                  // prefetch stays in flight
      asm volatile("s_waitcnt vmcnt(6)" ::: "memory"); // tile t landed; t+1 flying
    } else {
      asm volatile("s_waitcnt vmcnt(0)" ::: "memory");
    }
    __builtin_amdgcn_sched_barrier(0);
    __builtin_amdgcn_s_barrier();   // tile t visible to all waves
    __builtin_amdgcn_sched_barrier(0);

    const char* Kb = smem[buf];
    const char* Vb = smem[buf] + 12288;

    // all K fragments in registers (12 x ds_read_b128)
    bf16x8 af[3][4];
#pragma unroll
    for (int ks = 0; ks < 3; ++ks)
#pragma unroll
      for (int n = 0; n < 4; ++n)
        af[ks][n] = *reinterpret_cast<const bf16x8*>(Kb + (ks * 4 + n) * 1024 + lane * 16);

    // m-major QK: sc(m) complete after its 12 MFMA; exp/pack(m) overlaps QK(m+1)
    bf16x8 bp[4][2];
    __builtin_amdgcn_s_setprio(1);
#pragma unroll
    for (int m = 0; m < 4; ++m) {
      f32x4 sc[4] = {};
#pragma unroll
      for (int n = 0; n < 4; ++n) {
        sc[n] = mfma_bf16(af[0][n], aq[m][0], sc[n]);
        sc[n] = mfma_bf16(af[1][n], aq[m][1], sc[n]);
        sc[n] = mfma_bf16(af[2][n], aq[m][2], sc[n]);
      }
#pragma unroll
      for (int n = 0; n < 4; ++n)
#pragma unroll
        for (int j = 0; j < 4; ++j)
          bp[m][n >> 1][(n & 1) * 4 + j] = (__bf16)__builtin_amdgcn_exp2f(sc[n][j]);
    }
    __builtin_amdgcn_s_setprio(0);

    // O += P*V (V pre-permuted in global); den += ones*P on the MFMA pipe
    __builtin_amdgcn_s_setprio(1);
#pragma unroll
    for (int ks2 = 0; ks2 < 2; ++ks2) {
#pragma unroll
      for (int mf = 0; mf < 5; ++mf) {
        bf16x8 av = *reinterpret_cast<const bf16x8*>(Vb + (mf * 2 + ks2) * 1024 + lane * 16);
#pragma unroll
        for (int m = 0; m < 4; ++m)
          accO[mf][m] = mfma_bf16(av, bp[m][ks2], accO[mf][m]);
      }
#pragma unroll
      for (int m = 0; m < 4; ++m)
        accD[m] = mfma_bf16(one8, bp[m][ks2], accD[m]);
    }
    __builtin_amdgcn_s_setprio(0);

    __builtin_amdgcn_sched_barrier(0);
    __builtin_amdgcn_s_barrier();   // reads done -> next iter may overwrite buf^1
    __builtin_amdgcn_sched_barrier(0);
  }

  __syncthreads();

  // every lane holds den(q = w*64 + m*16 + lr) in accD[m][0]
  float rinv[4];
#pragma unroll
  for (int m = 0; m < 4; ++m) rinv[m] = 1.0f / accD[m][0];

  // O -> LDS (reuse smem: 256 rows x 160 B = 40 KB), coalesced global write
  char* sOut = smem[0];
#pragma unroll
  for (int mf = 0; mf < 5; ++mf)
#pragma unroll
    for (int m = 0; m < 4; ++m) {
      bf16x4 o4;
#pragma unroll
      for (int j = 0; j < 4; ++j) o4[j] = (__bf16)(accO[mf][m][j] * rinv[m]);
      *reinterpret_cast<bf16x4*>(sOut + (size_t)(w * 64 + m * 16 + lr) * 160 + (mf * 16 + lg * 4) * 2) = o4;
    }
  __syncthreads();

  const int b = bh >> 4, h = bh & 15;
#pragma unroll
  for (int i = 0; i < 10; ++i) {
    int c = i * 256 + tid;              // 0..2559: 256 rows x 10 slots
    int row = c / 10, slot = c - row * 10;
    int token = (qt * 256 + row) * 4 + b;
    *reinterpret_cast<bf16x8*>((char*)ow + (size_t)token * 2560 + h * 160 + slot * 16) =
        *reinterpret_cast<const bf16x8*>(sOut + row * 160 + slot * 16);
  }
}

// ---------------- launcher ----------------
extern "C" void kernel_launch(void* const* d_in, const int* in_sizes, int n_in,
                              void* d_out, int out_size, void* d_ws, size_t ws_size,
                              hipStream_t stream)
{
  const float* hidden = (const float*)d_in[0];
  const float* rot    = (const float*)d_in[1];
  const float* w1     = (const float*)d_in[2];
  const float* b1     = (const float*)d_in[3];
  const float* w2     = (const float*)d_in[4];
  const float* b2     = (const float*)d_in[5];
  float* out = (float*)d_out;

  char* ws = (char*)d_ws;
  __bf16* Xbf  = (__bf16*)(ws);                 // 8192x1280 bf16      = 20,971,520 B
  __bf16* W1bf = (__bf16*)(ws + 20971520);      // 3840x1280 bf16      =  9,830,400 B
  __bf16* W2bf = (__bf16*)(ws + 30801920);      // 1280x1280 bf16      =  3,276,800 B
  float*  ctab = (float*)(ws + 34078720);       // 2048x40 f32         =    327,680 B
  float*  stab = (float*)(ws + 34406400);       //                     =    327,680 B
  __bf16* qwp  = (__bf16*)(ws + 34734080);      // [B,H,S,80] bf16     = 20,971,520 B
  __bf16* kwp  = (__bf16*)(ws + 55705600);      // [B,H,S,80] bf16     = 20,971,520 B
  __bf16* vtwp = (__bf16*)(ws + 76677120);      // [B,H,80,S] bf16 (sigma-permuted) = 20,971,520 B
  __bf16* owp  = (__bf16*)(ws + 97648640);      // [S*B,1280] bf16     = 20,971,520 B
  float*  zp   = (float*)(ws + 118620160);      // 4KB zero page

  // 2621440 + 1228800 + 409600 + 81920 + 1024 = 4342784 threads
  prep_kernel<<<16964, 256, 0, stream>>>(hidden, w1, w2, rot, Xbf, W1bf, W2bf, ctab, stab, zp);

  gemm_qkv128<<<1920, 256, 0, stream>>>(Xbf, W1bf, b1, qwp, kwp, vtwp);

  const float qscale = 1.4426950408889634f / sqrtf(80.0f);  // scale * log2(e), folded into Q
  rope_kernel<<<10240, 256, 0, stream>>>(qwp, kwp, ctab, stab, qscale);

  attn_kernel<<<512, 256, 0, stream>>>(qwp, kwp, vtwp, owp, zp);

  gemm_out128<<<640, 256, 0, stream>>>(owp, W2bf, b2, out);
}

// Round 18
// 227.680 us; speedup vs baseline: 1.0935x; 1.0238x over previous
//
#include <hip/hip_runtime.h>
#include <hip/hip_bf16.h>
#include <math.h>

typedef __bf16 bf16x4 __attribute__((ext_vector_type(4)));
typedef __bf16 bf16x8 __attribute__((ext_vector_type(8)));
typedef float  f32x4  __attribute__((ext_vector_type(4)));

#define S_LEN 2048
#define BATCH 4
#define DMODEL 1280
#define NHEAD 16
#define DHEAD 80
#define KDIM 1280

__device__ __forceinline__ f32x4 mfma_bf16(bf16x8 a, bf16x8 b, f32x4 c) {
  return __builtin_amdgcn_mfma_f32_16x16x32_bf16(a, b, c, 0, 0, 0);
}

__device__ __forceinline__ void gload16(const void* g, void* l) {
  __builtin_amdgcn_global_load_lds(
      (const __attribute__((address_space(1))) unsigned int*)g,
      (__attribute__((address_space(3))) unsigned int*)l, 16, 0, 0);
}

// ---------------- merged prep: 3 casts + sincos table + zero page, ONE launch ----------------
__global__ void prep_kernel(const float* __restrict__ hidden, const float* __restrict__ w1,
                            const float* __restrict__ w2, const float* __restrict__ rot,
                            __bf16* __restrict__ Xbf, __bf16* __restrict__ W1bf,
                            __bf16* __restrict__ W2bf, float* __restrict__ ctab,
                            float* __restrict__ stab, float* __restrict__ zp)
{
  int i = blockIdx.x * 256 + threadIdx.x;
  if (i < 2621440) {
    float4 v = reinterpret_cast<const float4*>(hidden)[i];
    bf16x4 o;
    o[0] = (__bf16)v.x; o[1] = (__bf16)v.y; o[2] = (__bf16)v.z; o[3] = (__bf16)v.w;
    reinterpret_cast<bf16x4*>(Xbf)[i] = o;
    return;
  }
  i -= 2621440;
  if (i < 1228800) {
    float4 v = reinterpret_cast<const float4*>(w1)[i];
    bf16x4 o;
    o[0] = (__bf16)v.x; o[1] = (__bf16)v.y; o[2] = (__bf16)v.z; o[3] = (__bf16)v.w;
    reinterpret_cast<bf16x4*>(W1bf)[i] = o;
    return;
  }
  i -= 1228800;
  if (i < 409600) {
    float4 v = reinterpret_cast<const float4*>(w2)[i];
    bf16x4 o;
    o[0] = (__bf16)v.x; o[1] = (__bf16)v.y; o[2] = (__bf16)v.z; o[3] = (__bf16)v.w;
    reinterpret_cast<bf16x4*>(W2bf)[i] = o;
    return;
  }
  i -= 409600;
  if (i < 81920) {
    float v = rot[i];
    ctab[i] = cosf(v);
    stab[i] = sinf(v);
    return;
  }
  i -= 81920;
  if (i < 1024) zp[i] = 0.0f;
}

// ---------------- QKV GEMM, 128x128 tile, BK=64, 4 waves, SINGLE 32KB buffer ----------------
__global__ __launch_bounds__(256, 4) void gemm_qkv128(
    const __bf16* __restrict__ A, const __bf16* __restrict__ Bw,
    const float* __restrict__ bias,
    __bf16* __restrict__ qw, __bf16* __restrict__ kw, __bf16* __restrict__ vtw)
{
  __shared__ __align__(1024) char smem[32768];  // A 16KB | B 16KB; reused as C-tile in epilogue
  const int tid = threadIdx.x;
  const int lane = tid & 63;
  const int w = tid >> 6;             // 0..3
  const int lr = lane & 15, lg = lane >> 4;
  const int wr = w >> 1, wc = w & 1;  // wave owns rows wr*64..+64, cols wc*64..+64

  // XCD-chunked swizzle: 8 bx-panels per XCD (A slice 2.6 MB, L2-resident)
  const int wg = blockIdx.x;          // 0..1919
  const int xcd = wg & 7, idx = wg >> 3;  // idx 0..239
  const int bx = xcd * 8 + (idx & 7);
  const int by = idx >> 3;            // 0..29
  const int r0 = bx * 128, c0 = by * 128;
  const char* asrc = (const char*)(A + (size_t)r0 * KDIM);
  const char* bsrc = (const char*)(Bw + (size_t)c0 * KDIM);

  f32x4 acc[4][4] = {};

  for (int t = 0; t < 20; ++t) {
    const size_t kb = (size_t)t * 128;  // byte offset into K dim
#pragma unroll
    for (int i = 0; i < 8; ++i) {
      const int L = i * 4096 + tid * 16;           // 0..32767
      const int r = (L & 16383) >> 7;              // row within A or B panel
      const int coff = (L & 127) ^ ((r & 7) << 4); // inverse-swizzled source
      const char* s = (L < 16384 ? asrc : bsrc) + (size_t)r * 2560 + kb + coff;
      gload16(s, &smem[L]);
    }
    __syncthreads();  // drains vmcnt+lgkm; other blocks on the CU fill the gap

#pragma unroll
    for (int kk = 0; kk < 2; ++kk) {
      bf16x8 af[4], bfr[4];
#pragma unroll
      for (int rf = 0; rf < 4; ++rf) {
        const int row = wr * 64 + rf * 16 + lr;
        af[rf] = *reinterpret_cast<const bf16x8*>(
            &smem[row * 128 + ((kk * 64 + lg * 16) ^ ((row & 7) << 4))]);
      }
#pragma unroll
      for (int cf = 0; cf < 4; ++cf) {
        const int row = wc * 64 + cf * 16 + lr;
        bfr[cf] = *reinterpret_cast<const bf16x8*>(
            &smem[16384 + row * 128 + ((kk * 64 + lg * 16) ^ ((row & 7) << 4))]);
      }
#pragma unroll
      for (int rf = 0; rf < 4; ++rf)
#pragma unroll
        for (int cf = 0; cf < 4; ++cf)
          acc[rf][cf] = mfma_bf16(af[rf], bfr[cf], acc[rf][cf]);
    }
    __syncthreads();  // reads done -> next stage may overwrite
  }

  // ---- epilogue ----
  float biasr[4];
#pragma unroll
  for (int cf = 0; cf < 4; ++cf) biasr[cf] = bias[c0 + wc * 64 + cf * 16 + lr];

  // stage C-tile to LDS: row-major [128 rows][128 cols] bf16, col-XOR swizzle
#pragma unroll
  for (int cf = 0; cf < 4; ++cf) {
    const int col = wc * 64 + cf * 16 + lr;
#pragma unroll
    for (int rf = 0; rf < 4; ++rf)
#pragma unroll
      for (int j = 0; j < 4; ++j) {
        const int row = wr * 64 + rf * 16 + lg * 4 + j;
        *reinterpret_cast<__bf16*>(
            &smem[row * 256 + ((col ^ ((row & 7) << 3)) << 1)]) =
            (__bf16)(acc[rf][cf][j] + biasr[cf]);
      }
  }
  __syncthreads();

  const int which = c0 / DMODEL;          // 0=q, 1=k, 2=v (block-uniform)
  const int ee0 = c0 - which * DMODEL;    // channel base within {q,k,v}

  if (which < 2) {
    __bf16* dst = (which == 0) ? qw : kw;
#pragma unroll
    for (int i = 0; i < 8; ++i) {
      const int cid = i * 256 + tid;      // 0..2047
      const int row = cid >> 4, slot = cid & 15;
      bf16x8 v = *reinterpret_cast<const bf16x8*>(
          &smem[row * 256 + ((slot ^ (row & 7)) << 4)]);
      const int tr = r0 + row;
      const int b = tr & 3, stok = tr >> 2;
      const int ee = ee0 + slot * 8;      // 8-aligned; 8|80 -> never straddles a head
      const int h = ee / DHEAD, dh = ee - h * DHEAD;
      *reinterpret_cast<bf16x8*>(
          &dst[((size_t)(b * NHEAD + h) * S_LEN + stok) * DHEAD + dh]) = v;
    }
  } else {
    const int s0 = r0 >> 2;               // 32-aligned token/4 base
#pragma unroll
    for (int i = 0; i < 8; ++i) {
      const int cid = i * 256 + tid;      // 0..2047
      const int col = cid >> 4;           // channel within tile, 0..127
      const int b = (cid >> 2) & 3, spblk = cid & 3;
      bf16x8 v;
#pragma unroll
      for (int k = 0; k < 8; ++k) {
        const int spl = spblk * 8 + k;
        // inverse sigma: s = (sp&3) | ((sp&24)>>1) | ((sp&4)<<2)
        const int sl = (spl & 3) | ((spl & 24) >> 1) | ((spl & 4) << 2);
        const int row = sl * 4 + b;
        v[k] = *reinterpret_cast<const __bf16*>(
            &smem[row * 256 + ((col ^ ((row & 7) << 3)) << 1)]);
      }
      const int ee = ee0 + col;
      const int h = ee / DHEAD, dh = ee - h * DHEAD;
      *reinterpret_cast<bf16x8*>(
          &vtw[((size_t)(b * NHEAD + h) * DHEAD + dh) * S_LEN + s0 + spblk * 8]) = v;
    }
  }
}

// ---------------- out-proj GEMM, 128x128, SINGLE 32KB buffer ----------------
__global__ __launch_bounds__(256, 4) void gemm_out128(
    const __bf16* __restrict__ A, const __bf16* __restrict__ Bw,
    const float* __restrict__ bias, float* __restrict__ outf)
{
  __shared__ __align__(1024) char smem[32768];  // A 16KB | B 16KB
  const int tid = threadIdx.x;
  const int lane = tid & 63;
  const int w = tid >> 6;
  const int lr = lane & 15, lg = lane >> 4;
  const int wr = w >> 1, wc = w & 1;

  const int wg = blockIdx.x;          // 0..639
  const int xcd = wg & 7, idx = wg >> 3;  // idx 0..79
  const int bx = xcd * 8 + (idx & 7);
  const int by = idx >> 3;            // 0..9
  const int r0 = bx * 128, c0 = by * 128;
  const char* asrc = (const char*)(A + (size_t)r0 * KDIM);
  const char* bsrc = (const char*)(Bw + (size_t)c0 * KDIM);

  f32x4 acc[4][4] = {};

  for (int t = 0; t < 20; ++t) {
    const size_t kb = (size_t)t * 128;
#pragma unroll
    for (int i = 0; i < 8; ++i) {
      const int L = i * 4096 + tid * 16;
      const int r = (L & 16383) >> 7;
      const int coff = (L & 127) ^ ((r & 7) << 4);
      const char* s = (L < 16384 ? asrc : bsrc) + (size_t)r * 2560 + kb + coff;
      gload16(s, &smem[L]);
    }
    __syncthreads();

#pragma unroll
    for (int kk = 0; kk < 2; ++kk) {
      bf16x8 af[4], bfr[4];
#pragma unroll
      for (int rf = 0; rf < 4; ++rf) {
        const int row = wr * 64 + rf * 16 + lr;
        af[rf] = *reinterpret_cast<const bf16x8*>(
            &smem[row * 128 + ((kk * 64 + lg * 16) ^ ((row & 7) << 4))]);
      }
#pragma unroll
      for (int cf = 0; cf < 4; ++cf) {
        const int row = wc * 64 + cf * 16 + lr;
        bfr[cf] = *reinterpret_cast<const bf16x8*>(
            &smem[16384 + row * 128 + ((kk * 64 + lg * 16) ^ ((row & 7) << 4))]);
      }
#pragma unroll
      for (int rf = 0; rf < 4; ++rf)
#pragma unroll
        for (int cf = 0; cf < 4; ++cf)
          acc[rf][cf] = mfma_bf16(af[rf], bfr[cf], acc[rf][cf]);
    }
    __syncthreads();
  }

  float biasr[4];
#pragma unroll
  for (int cf = 0; cf < 4; ++cf) biasr[cf] = bias[c0 + wc * 64 + cf * 16 + lr];

#pragma unroll
  for (int rf = 0; rf < 4; ++rf)
#pragma unroll
    for (int cf = 0; cf < 4; ++cf) {
      const int c = c0 + wc * 64 + cf * 16 + lr;
#pragma unroll
      for (int j = 0; j < 4; ++j) {
        const int r = r0 + wr * 64 + rf * 16 + lg * 4 + j;
        outf[(size_t)r * DMODEL + c] = acc[rf][cf][j] + biasr[cf];
      }
    }
}

// ---------------- RoPE in-place on q,k; q additionally pre-scaled by scale*log2e ----------------
__global__ void rope_kernel(__bf16* __restrict__ qw, __bf16* __restrict__ kw,
                            const float* __restrict__ ctab, const float* __restrict__ stab,
                            float qscale)
{
  int idx = blockIdx.x * 256 + threadIdx.x;  // 2*64*2048*10 threads
  const int j = idx % 10;
  int rest = idx / 10;
  const int s = rest & (S_LEN - 1);
  rest >>= 11;
  const int bh = rest & 63;
  const int isk = rest >> 6;
  __bf16* base = (isk ? kw : qw) + ((size_t)bh * S_LEN + s) * DHEAD;
  const float4 c4 = *reinterpret_cast<const float4*>(ctab + s * 40 + j * 4);
  const float4 s4 = *reinterpret_cast<const float4*>(stab + s * 40 + j * 4);
  bf16x4 a = *reinterpret_cast<bf16x4*>(base + j * 4);
  bf16x4 b = *reinterpret_cast<bf16x4*>(base + 40 + j * 4);
  const float m = isk ? 1.0f : qscale;
  const float cc[4] = {c4.x, c4.y, c4.z, c4.w};
  const float ss[4] = {s4.x, s4.y, s4.z, s4.w};
#pragma unroll
  for (int t = 0; t < 4; ++t) {
    float fa = (float)a[t], fb = (float)b[t];
    a[t] = (__bf16)((fa * cc[t] - fb * ss[t]) * m);
    b[t] = (__bf16)((fb * cc[t] + fa * ss[t]) * m);
  }
  *reinterpret_cast<bf16x4*>(base + j * 4) = a;
  *reinterpret_cast<bf16x4*>(base + 40 + j * 4) = b;
}

// ---------------- attention v10 (R16-proven: n-major QK + setprio clusters) ----------------
__global__ __launch_bounds__(256, 2) void attn_kernel(
    const __bf16* __restrict__ qw, const __bf16* __restrict__ kw,
    const __bf16* __restrict__ vtw, __bf16* __restrict__ ow,
    const float* __restrict__ zp)
{
  __shared__ __align__(1024) char smem[2][24576];  // [buf][K 12KB | V 10KB | 2KB trash]

  const int tid = threadIdx.x;
  const int lane = tid & 63;
  const int w = tid >> 6;             // 0..3
  const int lr = lane & 15, lg = lane >> 4;

  // XCD-aware mapping: all 8 q-tiles of one bh on one XCD
  const int wg = blockIdx.x;          // 0..511
  const int local = wg >> 3;          // 0..63
  const int bh = (wg & 7) * 8 + (local >> 3);
  const int qt = local & 7;

  const char* qbase = (const char*)(qw + ((size_t)bh * S_LEN + qt * 256) * DHEAD);
  const char* kbase = (const char*)(kw + (size_t)bh * S_LEN * DHEAD);
  const char* vbase = (const char*)(vtw + (size_t)bh * DHEAD * S_LEN);
  const char* zpb = (const char*)zp;

  bf16x8 z8, one8;
#pragma unroll
  for (int i = 0; i < 8; ++i) { z8[i] = (__bf16)0.0f; one8[i] = (__bf16)1.0f; }

  // Q fragments (B-operand): q = w*64 + m*16 + lr, d-chunks {0..31,32..63,64..79+pad}
  bf16x8 aq[4][3];
#pragma unroll
  for (int m = 0; m < 4; ++m) {
    const char* rp = qbase + (size_t)(w * 64 + m * 16 + lr) * 160;
    aq[m][0] = *reinterpret_cast<const bf16x8*>(rp + lg * 16);
    aq[m][1] = *reinterpret_cast<const bf16x8*>(rp + 64 + lg * 16);
    aq[m][2] = (lg < 2) ? *reinterpret_cast<const bf16x8*>(rp + 128 + lg * 16) : z8;
  }

  // Hoisted staging sources: wave w owns slots w*6..w*6+5 of 24 x 1KB slots.
  const char* src[6];
  size_t step[6];
#pragma unroll
  for (int i = 0; i < 6; ++i) {
    const int s = w * 6 + i;
    if (s < 12) {
      const int ks = s >> 2, n = s & 3;
      if (ks == 2 && lg >= 2) { src[i] = zpb + lane * 16; step[i] = 0; }
      else { src[i] = kbase + (size_t)(n * 16 + lr) * 160 + ks * 64 + lg * 16; step[i] = 64 * 160; }
    } else {
      const int v = s - 12, mf = v >> 1, ks2 = v & 1;
      if (mf == 5) { src[i] = zpb + lane * 16; step[i] = 0; }
      else { src[i] = vbase + (size_t)(mf * 16 + lr) * 4096 + (size_t)(ks2 * 32 + lg * 8) * 2; step[i] = 128; }
    }
  }

  auto stage = [&](int buf) {
#pragma unroll
    for (int i = 0; i < 6; ++i) {
      gload16(src[i], &smem[buf][(w * 6 + i) * 1024]);
      src[i] += step[i];
    }
  };

  f32x4 accO[5][4] = {};  // O[dh = mf*16+lg*4+j][q = w*64 + m*16 + lr]
  f32x4 accD[4] = {};     // den(q=lr) per m via ones-MFMA

  stage(0);
  asm volatile("s_waitcnt vmcnt(0)" ::: "memory");
  __builtin_amdgcn_s_barrier();
  __builtin_amdgcn_sched_barrier(0);

  for (int t = 0; t < 32; ++t) {
    const int buf = t & 1;
    if (t < 31) {
      stage(buf ^ 1);                                  // prefetch stays in flight
      asm volatile("s_waitcnt vmcnt(6)" ::: "memory"); // tile t landed; t+1 flying
    } else {
      asm volatile("s_waitcnt vmcnt(0)" ::: "memory");
    }
    __builtin_amdgcn_sched_barrier(0);
    __builtin_amdgcn_s_barrier();   // tile t visible to all waves
    __builtin_amdgcn_sched_barrier(0);

    const char* Kb = smem[buf];
    const char* Vb = smem[buf] + 12288;

    // S^T = K * Q^T for 4 Q-blocks (af fragments reused across m)
    f32x4 sc[4][4] = {};
    __builtin_amdgcn_s_setprio(1);
#pragma unroll
    for (int n = 0; n < 4; ++n) {
      bf16x8 af0 = *reinterpret_cast<const bf16x8*>(Kb + (0 * 4 + n) * 1024 + lane * 16);
      bf16x8 af1 = *reinterpret_cast<const bf16x8*>(Kb + (1 * 4 + n) * 1024 + lane * 16);
      bf16x8 af2 = *reinterpret_cast<const bf16x8*>(Kb + (2 * 4 + n) * 1024 + lane * 16);
#pragma unroll
      for (int m = 0; m < 4; ++m) {
        sc[m][n] = mfma_bf16(af0, aq[m][0], sc[m][n]);
        sc[m][n] = mfma_bf16(af1, aq[m][1], sc[m][n]);
        sc[m][n] = mfma_bf16(af2, aq[m][2], sc[m][n]);
      }
    }
    __builtin_amdgcn_s_setprio(0);

    // p = exp2(s); lane-local P pack (permuted k-order)
    bf16x8 bp[4][2];
#pragma unroll
    for (int m = 0; m < 4; ++m)
#pragma unroll
      for (int n = 0; n < 4; ++n) {
#pragma unroll
        for (int j = 0; j < 4; ++j)
          bp[m][n >> 1][(n & 1) * 4 + j] = (__bf16)__builtin_amdgcn_exp2f(sc[m][n][j]);
      }

    // O += P*V (V pre-permuted in global); den += ones*P on the MFMA pipe
    __builtin_amdgcn_s_setprio(1);
#pragma unroll
    for (int ks2 = 0; ks2 < 2; ++ks2) {
#pragma unroll
      for (int mf = 0; mf < 5; ++mf) {
        bf16x8 av = *reinterpret_cast<const bf16x8*>(Vb + (mf * 2 + ks2) * 1024 + lane * 16);
#pragma unroll
        for (int m = 0; m < 4; ++m)
          accO[mf][m] = mfma_bf16(av, bp[m][ks2], accO[mf][m]);
      }
#pragma unroll
      for (int m = 0; m < 4; ++m)
        accD[m] = mfma_bf16(one8, bp[m][ks2], accD[m]);
    }
    __builtin_amdgcn_s_setprio(0);

    __builtin_amdgcn_sched_barrier(0);
    __builtin_amdgcn_s_barrier();   // reads done -> next iter may overwrite buf^1
    __builtin_amdgcn_sched_barrier(0);
  }

  __syncthreads();

  // every lane holds den(q = w*64 + m*16 + lr) in accD[m][0]
  float rinv[4];
#pragma unroll
  for (int m = 0; m < 4; ++m) rinv[m] = 1.0f / accD[m][0];

  // O -> LDS (reuse smem: 256 rows x 160 B = 40 KB), coalesced global write
  char* sOut = smem[0];
#pragma unroll
  for (int mf = 0; mf < 5; ++mf)
#pragma unroll
    for (int m = 0; m < 4; ++m) {
      bf16x4 o4;
#pragma unroll
      for (int j = 0; j < 4; ++j) o4[j] = (__bf16)(accO[mf][m][j] * rinv[m]);
      *reinterpret_cast<bf16x4*>(sOut + (size_t)(w * 64 + m * 16 + lr) * 160 + (mf * 16 + lg * 4) * 2) = o4;
    }
  __syncthreads();

  const int b = bh >> 4, h = bh & 15;
#pragma unroll
  for (int i = 0; i < 10; ++i) {
    int c = i * 256 + tid;              // 0..2559: 256 rows x 10 slots
    int row = c / 10, slot = c - row * 10;
    int token = (qt * 256 + row) * 4 + b;
    *reinterpret_cast<bf16x8*>((char*)ow + (size_t)token * 2560 + h * 160 + slot * 16) =
        *reinterpret_cast<const bf16x8*>(sOut + row * 160 + slot * 16);
  }
}

// ---------------- launcher ----------------
extern "C" void kernel_launch(void* const* d_in, const int* in_sizes, int n_in,
                              void* d_out, int out_size, void* d_ws, size_t ws_size,
                              hipStream_t stream)
{
  const float* hidden = (const float*)d_in[0];
  const float* rot    = (const float*)d_in[1];
  const float* w1     = (const float*)d_in[2];
  const float* b1     = (const float*)d_in[3];
  const float* w2     = (const float*)d_in[4];
  const float* b2     = (const float*)d_in[5];
  float* out = (float*)d_out;

  char* ws = (char*)d_ws;
  __bf16* Xbf  = (__bf16*)(ws);                 // 8192x1280 bf16      = 20,971,520 B
  __bf16* W1bf = (__bf16*)(ws + 20971520);      // 3840x1280 bf16      =  9,830,400 B
  __bf16* W2bf = (__bf16*)(ws + 30801920);      // 1280x1280 bf16      =  3,276,800 B
  float*  ctab = (float*)(ws + 34078720);       // 2048x40 f32         =    327,680 B
  float*  stab = (float*)(ws + 34406400);       //                     =    327,680 B
  __bf16* qwp  = (__bf16*)(ws + 34734080);      // [B,H,S,80] bf16     = 20,971,520 B
  __bf16* kwp  = (__bf16*)(ws + 55705600);      // [B,H,S,80] bf16     = 20,971,520 B
  __bf16* vtwp = (__bf16*)(ws + 76677120);      // [B,H,80,S] bf16 (sigma-permuted) = 20,971,520 B
  __bf16* owp  = (__bf16*)(ws + 97648640);      // [S*B,1280] bf16     = 20,971,520 B
  float*  zp   = (float*)(ws + 118620160);      // 4KB zero page

  // 2621440 + 1228800 + 409600 + 81920 + 1024 = 4342784 threads
  prep_kernel<<<16964, 256, 0, stream>>>(hidden, w1, w2, rot, Xbf, W1bf, W2bf, ctab, stab, zp);

  gemm_qkv128<<<1920, 256, 0, stream>>>(Xbf, W1bf, b1, qwp, kwp, vtwp);

  const float qscale = 1.4426950408889634f / sqrtf(80.0f);  // scale * log2(e), folded into Q
  rope_kernel<<<10240, 256, 0, stream>>>(qwp, kwp, ctab, stab, qscale);

  attn_kernel<<<512, 256, 0, stream>>>(qwp, kwp, vtwp, owp, zp);

  gemm_out128<<<640, 256, 0, stream>>>(owp, W2bf, b2, out);
}